// Round 5
// baseline (272.195 us; speedup 1.0000x reference)
//
#include <hip/hip_runtime.h>
#include <hip/hip_bf16.h>

#define Nn 8192
#define Dd 512
#define KK 16
#define CC 32      // merged candidates per row (rescore input)
#define CSUB 8     // candidates kept per substream reservoir
#define TI 128
#define TJ 128
#define BKc 64
#define JSPLIT 32  // 32 J-chunks of 256 rows; 4 per XCD
#define JTILES 2   // 256 / TJ
#define NSUB (JSPLIT * 2)    // 64 substreams per row
#define PENT (NSUB * CSUB)   // 512 partial entries per row

typedef short bf16x8 __attribute__((ext_vector_type(8)));
typedef float f32x4 __attribute__((ext_vector_type(4)));
typedef unsigned int uint32;

__device__ __forceinline__ uint32 med3u(uint32 a, uint32 b, uint32 c) {
  uint32 d;
  asm("v_med3_u32 %0, %1, %2, %3" : "=v"(d) : "v"(a), "v"(b), "v"(c));
  return d;
}

// Branchless top-k (smallest keys) in a descending-sorted register array.
template <int CCn>
__device__ __forceinline__ void topk_insert(uint32* h, uint32 v) {
#pragma unroll
  for (int s = 0; s < CCn - 1; ++s) h[s] = med3u(h[s], h[s + 1], v);
  h[CCn - 1] = (h[CCn - 1] < v) ? h[CCn - 1] : v;
}

__device__ __forceinline__ void gload_lds16(const void* g, void* l) {
  __builtin_amdgcn_global_load_lds(
      (const __attribute__((address_space(1))) unsigned int*)g,
      (__attribute__((address_space(3))) unsigned int*)l, 16, 0, 0);
}

// ---------------- Kernel A: fp32 -> bf16 copy + row sq-norms ----------------
__global__ void knn_prep(const float* __restrict__ x, uint32* __restrict__ xbu,
                         float* __restrict__ sq) {
  const int row = blockIdx.x * 4 + (threadIdx.x >> 6);
  const int l = threadIdx.x & 63;
  const float2* xr = (const float2*)(x + (size_t)row * Dd);
  float s = 0.f;
#pragma unroll
  for (int q = 0; q < 4; ++q) {
    float2 v = xr[q * 64 + l];
    s = fmaf(v.x, v.x, s);
    s = fmaf(v.y, v.y, s);
    uint32 ux = __builtin_bit_cast(uint32, v.x);
    uint32 uy = __builtin_bit_cast(uint32, v.y);
    uint32 bx = (ux + 0x7FFFu + ((ux >> 16) & 1u)) >> 16;  // RNE to bf16
    uint32 by = (uy + 0x7FFFu + ((uy >> 16) & 1u)) >> 16;
    xbu[(size_t)row * (Dd / 2) + q * 64 + l] = bx | (by << 16);
  }
#pragma unroll
  for (int off = 32; off > 0; off >>= 1) s += __shfl_down(s, off);
  if (l == 0) sq[row] = s;
}

// ------- Kernel B: pipelined bf16-MFMA Gram tile + per-substream top-8 -------
// 2-D XCD partition: xcd=bid&7 owns a 1MB J-slice (4 sub-chunks of 256 rows);
// ib=bid>>5 keeps any 512-resident window to 16 A-tiles (2MB). A+B fit L2.
__global__ __launch_bounds__(256, 2) void knn_cand(
    const unsigned short* __restrict__ xb, const float* __restrict__ sq,
    uint32* __restrict__ partials) {
  __shared__ __align__(16) unsigned short stageS[2][TI * BKc * 2];  // 64 KB
  __shared__ float sqj[TJ];

  const int bid = blockIdx.x;
  const int xcd = bid & 7;
  const int jc = xcd * 4 + ((bid >> 3) & 3);  // [0,32)
  const int ib = bid >> 5;                    // [0,64)
  const int t = threadIdx.x;
  const int w = t >> 6;
  const int l = t & 63;
  const int wrow = w >> 1, wcol = w & 1;
  const int l16 = l & 15, lq = l >> 4;

  const int row_s = t >> 1;
  const int hv = t & 1;
  const int irow_g = ib * TI + row_s;
  const int arow0 = ib * TI;

  float (*d2s)[32] = (float(*)[32])(void*)stageS[1];

#define STAGE(buf, brow0, kkk)                                              \
  do {                                                                      \
    _Pragma("unroll") for (int u = 0; u < 4; ++u) {                         \
      const int ch = w * 4 + u;                                             \
      const int r = ch * 8 + (l >> 3);                                      \
      const int cs = ((l & 7) ^ (r & 7)) * 8;                               \
      gload_lds16(xb + (size_t)(arow0 + r) * Dd + (kkk)*BKc + cs,           \
                  (void*)(stageS[buf] + ch * 512));                         \
      gload_lds16(xb + (size_t)(brow0 + r) * Dd + (kkk)*BKc + cs,           \
                  (void*)(stageS[buf] + TI * BKc + ch * 512));              \
    }                                                                       \
  } while (0)

  uint32 heap[CSUB];
#pragma unroll
  for (int s = 0; s < CSUB; ++s) heap[s] = 0xFFFFFFFFu;

  const int jbase0 = jc * (Nn / JSPLIT);
  STAGE(0, jbase0, 0);  // prologue: jt=0, kk=0 into buf0

  for (int jt = 0; jt < JTILES; ++jt) {
    const int jbase = jbase0 + jt * TJ;
    __syncthreads();  // [A] drains prologue / cross-jt prefetch; protects d2s

    f32x4 acc[4][4];
#pragma unroll
    for (int a = 0; a < 4; ++a)
#pragma unroll
      for (int b = 0; b < 4; ++b) acc[a][b] = (f32x4){0.f, 0.f, 0.f, 0.f};

#pragma unroll
    for (int kk = 0; kk < Dd / BKc; ++kk) {
      const int cb = kk & 1;
      if (kk < Dd / BKc - 1) {
        STAGE(cb ^ 1, jbase, kk + 1);
      } else if (jt < JTILES - 1) {
        STAGE(cb ^ 1, jbase + TJ, 0);  // cross-jt prefetch (lands during scan)
      }
      const unsigned short* AL = stageS[cb];
      const unsigned short* BLp = stageS[cb] + TI * BKc;
#pragma unroll
      for (int ks = 0; ks < 2; ++ks) {
        bf16x8 af[4], bfr[4];
#pragma unroll
        for (int fi = 0; fi < 4; ++fi) {
          const int R = wrow * 64 + fi * 16 + l16;
          af[fi] = *(const bf16x8*)&AL[R * BKc +
                                       ((ks * 32 + lq * 8) ^ ((R & 7) * 8))];
        }
#pragma unroll
        for (int fj = 0; fj < 4; ++fj) {
          const int R = wcol * 64 + fj * 16 + l16;
          bfr[fj] = *(const bf16x8*)&BLp[R * BKc +
                                         ((ks * 32 + lq * 8) ^ ((R & 7) * 8))];
        }
#pragma unroll
        for (int fi = 0; fi < 4; ++fi)
#pragma unroll
          for (int fj = 0; fj < 4; ++fj)
            acc[fi][fj] = __builtin_amdgcn_mfma_f32_16x16x32_bf16(
                af[fi], bfr[fj], acc[fi][fj], 0, 0, 0);
      }
      __syncthreads();  // [C] drains this kk's prefetch; orders buffer reuse
    }

    if (t < TJ) sqj[t] = sq[jbase + t];

    // Four 32-col phases: stage dots to d2s (aliases buf1, free now), scan.
#pragma unroll
    for (int p = 0; p < 4; ++p) {
      __syncthreads();  // [D] previous phase's scan reads done (+sqj visible)
      if (wcol == (p >> 1)) {
        const int fjp = p & 1;
#pragma unroll
        for (int fi = 0; fi < 4; ++fi)
#pragma unroll
          for (int fjh = 0; fjh < 2; ++fjh) {
            const int fj = fjp * 2 + fjh;
#pragma unroll
            for (int r = 0; r < 4; ++r) {
              const int row = wrow * 64 + fi * 16 + lq * 4 + r;
              const int c = fjh * 16 + l16;
              const int cs2 = (((c >> 2) ^ (row & 7)) << 2) | (c & 3);
              d2s[row][cs2] = acc[fi][fj][r];
            }
          }
      }
      __syncthreads();  // [E] d2s writes visible
      const uint32 jg0 = (uint32)(jbase + p * 32 + hv * 16);
#pragma unroll
      for (int u2 = 0; u2 < 4; ++u2) {
        const int chunk = (hv * 4 + u2) ^ (row_s & 7);
        float4 v = *(const float4*)&d2s[row_s][chunk * 4];
        float vv[4] = {v.x, v.y, v.z, v.w};
#pragma unroll
        for (int e = 0; e < 4; ++e) {
          float key =
              fmaxf(fmaf(-2.f, vv[e], sqj[p * 32 + hv * 16 + u2 * 4 + e]), 0.f);
          uint32 packed = (__builtin_bit_cast(uint32, key) & 0xFFFFE000u) |
                          (jg0 + (uint32)(u2 * 4 + e));
          topk_insert<CSUB>(heap, packed);  // self removed later in rescore
        }
      }
    }
  }

  const int sub = jc * 2 + hv;  // [0,64)
#pragma unroll
  for (int s = 0; s < CSUB; ++s)
    partials[(size_t)irow_g * PENT + sub * CSUB + s] = heap[s];
#undef STAGE
}

// ---- Kernel C: bitonic-512 merge -> fp64 rescore (rows in regs) -> average ----
__global__ __launch_bounds__(256) void knn_rescore(
    const float* __restrict__ x, const uint32* __restrict__ partials,
    float* __restrict__ out) {
  __shared__ uint32 keyS[PENT];      // 2 KB
  __shared__ int candS[CC];
  __shared__ double d2S[CC];
  __shared__ int selB[CC];
  __shared__ float obuf[4][Dd];      // 8 KB wave-partial sums
  const int row = blockIdx.x;
  const int t = threadIdx.x, w = t >> 6, l = t & 63;

  {
    uint2 v2 = *(const uint2*)&partials[(size_t)row * PENT + 2 * t];
    uint32 a = v2.x, b = v2.y;
    if ((a & 0x1FFFu) == (uint32)row) a = 0xFFFFFFFFu;
    if ((b & 0x1FFFu) == (uint32)row) b = 0xFFFFFFFFu;
    keyS[2 * t] = a;
    keyS[2 * t + 1] = b;
  }
  // Bitonic sort 512 keys ascending (keys distinct -> total order).
  for (int k = 2; k <= PENT; k <<= 1) {
    for (int j = k >> 1; j > 0; j >>= 1) {
      __syncthreads();
#pragma unroll
      for (int h = 0; h < 2; ++h) {
        const int e = t + h * 256;
        if ((e & j) == 0) {
          const int pp = e | j;
          uint32 a = keyS[e], b = keyS[pp];
          if ((a > b) == ((e & k) == 0)) {
            keyS[e] = b;
            keyS[pp] = a;
          }
        }
      }
    }
  }
  __syncthreads();
  if (t < CC) candS[t] = (int)(keyS[t] & 0x1FFFu);
  __syncthreads();

  // fp64 rescore; keep candidate row data in registers for the average.
  const float4* x4 = (const float4*)x;
  float4 xi0 = x4[(size_t)row * 128 + l];
  float4 xi1 = x4[(size_t)row * 128 + 64 + l];
  float4 rb0[8], rb1[8];
#pragma unroll
  for (int u = 0; u < 8; ++u) {
    const int c = w * 8 + u;
    const int j = candS[c];
    rb0[u] = x4[(size_t)j * 128 + l];
    rb1[u] = x4[(size_t)j * 128 + 64 + l];
    double s = 0.0;
    double d0 = (double)xi0.x - (double)rb0[u].x;
    double d1 = (double)xi0.y - (double)rb0[u].y;
    double d2 = (double)xi0.z - (double)rb0[u].z;
    double d3 = (double)xi0.w - (double)rb0[u].w;
    s = fma(d0, d0, s); s = fma(d1, d1, s); s = fma(d2, d2, s); s = fma(d3, d3, s);
    d0 = (double)xi1.x - (double)rb1[u].x;
    d1 = (double)xi1.y - (double)rb1[u].y;
    d2 = (double)xi1.z - (double)rb1[u].z;
    d3 = (double)xi1.w - (double)rb1[u].w;
    s = fma(d0, d0, s); s = fma(d1, d1, s); s = fma(d2, d2, s); s = fma(d3, d3, s);
#pragma unroll
    for (int off = 32; off > 0; off >>= 1) s += __shfl_down(s, off);
    if (l == 0) d2S[c] = s;
  }
  __syncthreads();
  if (t < CC) {
    const double mine = d2S[t];
    const int mi = candS[t];
    int rank = 0;
#pragma unroll
    for (int o = 0; o < CC; ++o) {
      double vo = d2S[o];
      int io = candS[o];
      if (vo < mine || (vo == mine && io < mi)) rank++;
    }
    selB[t] = (rank < KK) ? 1 : 0;
  }
  __syncthreads();

  // Per-wave partial sums over selected candidates (from registers).
  float4 s0 = (float4){0.f, 0.f, 0.f, 0.f}, s1 = (float4){0.f, 0.f, 0.f, 0.f};
#pragma unroll
  for (int u = 0; u < 8; ++u) {
    if (selB[w * 8 + u]) {
      s0.x += rb0[u].x; s0.y += rb0[u].y; s0.z += rb0[u].z; s0.w += rb0[u].w;
      s1.x += rb1[u].x; s1.y += rb1[u].y; s1.z += rb1[u].z; s1.w += rb1[u].w;
    }
  }
  *(float4*)&obuf[w][l * 4] = s0;
  *(float4*)&obuf[w][256 + l * 4] = s1;
  __syncthreads();
  const int d0i = 2 * t;
  float o0 = (obuf[0][d0i] + obuf[1][d0i] + obuf[2][d0i] + obuf[3][d0i]) * 0.0625f;
  float o1 = (obuf[0][d0i + 1] + obuf[1][d0i + 1] + obuf[2][d0i + 1] +
              obuf[3][d0i + 1]) * 0.0625f;
  ((float2*)out)[(size_t)row * 256 + t] = make_float2(o0, o1);
}

extern "C" void kernel_launch(void* const* d_in, const int* in_sizes, int n_in,
                              void* d_out, int out_size, void* d_ws,
                              size_t ws_size, hipStream_t stream) {
  const float* x = (const float*)d_in[0];
  float* out = (float*)d_out;
  char* ws = (char*)d_ws;
  // ws layout: xb (8MB) | sq (32KB) | partials (16MB)  => 24.2 MB
  unsigned short* xb = (unsigned short*)ws;
  float* sq = (float*)(ws + (size_t)Nn * Dd * 2);
  uint32* partials = (uint32*)(ws + (size_t)Nn * Dd * 2 + (size_t)Nn * 4);

  knn_prep<<<Nn / 4, 256, 0, stream>>>(x, (uint32*)xb, sq);
  knn_cand<<<64 * JSPLIT, 256, 0, stream>>>(xb, sq, partials);
  knn_rescore<<<Nn, 256, 0, stream>>>(x, partials, out);
}

// Round 6
// 180.163 us; speedup vs baseline: 1.5108x; 1.5108x over previous
//
#include <hip/hip_runtime.h>
#include <hip/hip_bf16.h>

#define Nn 8192
#define Dd 512
#define KK 16
#define CC 32      // merged candidates per row (rescore input)
#define CSUB 8     // candidates kept per substream reservoir
#define TI 128
#define TJ 128
#define BKc 64
#define JSPLIT 32  // 32 J-chunks of 256 rows; 4 per XCD
#define JTILES 2   // 256 / TJ
#define NSUB (JSPLIT * 2)    // 64 substreams per row
#define PENT (NSUB * CSUB)   // 512 partial entries per row

typedef short bf16x8 __attribute__((ext_vector_type(8)));
typedef float f32x4 __attribute__((ext_vector_type(4)));
typedef unsigned int uint32;

__device__ __forceinline__ uint32 med3u(uint32 a, uint32 b, uint32 c) {
  uint32 d;
  asm("v_med3_u32 %0, %1, %2, %3" : "=v"(d) : "v"(a), "v"(b), "v"(c));
  return d;
}

// Branchless top-k (smallest keys) in a descending-sorted register array.
template <int CCn>
__device__ __forceinline__ void topk_insert(uint32* h, uint32 v) {
#pragma unroll
  for (int s = 0; s < CCn - 1; ++s) h[s] = med3u(h[s], h[s + 1], v);
  h[CCn - 1] = (h[CCn - 1] < v) ? h[CCn - 1] : v;
}

__device__ __forceinline__ void gload_lds16(const void* g, void* l) {
  __builtin_amdgcn_global_load_lds(
      (const __attribute__((address_space(1))) unsigned int*)g,
      (__attribute__((address_space(3))) unsigned int*)l, 16, 0, 0);
}

// ---- Barrier-free bitonic: compare-exchange with shfl partner (j <= 32) ----
__device__ __forceinline__ uint32 cswap(uint32 v, int j, bool asc, int lane) {
  uint32 pv = (uint32)__shfl_xor((int)v, j, 64);
  uint32 mn = v < pv ? v : pv;
  uint32 mx = v < pv ? pv : v;
  const bool lower = ((lane & j) == 0);
  return (asc == lower) ? mn : mx;
}

// Full ascending sort of 128 uint keys held 2-per-lane across one wave.
// Layout: v0 at position p=lane, v1 at position p=64+lane.
__device__ __forceinline__ void sort128(uint32& v0, uint32& v1, int lane) {
#pragma unroll
  for (int k = 2; k <= 32; k <<= 1) {
#pragma unroll
    for (int j = k >> 1; j > 0; j >>= 1) {
      const bool asc = ((lane & k) == 0);
      v0 = cswap(v0, j, asc, lane);
      v1 = cswap(v1, j, asc, lane);
    }
  }
  // k = 64: p0 block ascending, p1 block descending
#pragma unroll
  for (int j = 32; j > 0; j >>= 1) {
    v0 = cswap(v0, j, true, lane);
    v1 = cswap(v1, j, false, lane);
  }
  // k = 128: j=64 is the in-lane register pair, then j<=32 shfl, all ascending
  {
    uint32 mn = v0 < v1 ? v0 : v1;
    uint32 mx = v0 < v1 ? v1 : v0;
    v0 = mn;
    v1 = mx;
  }
#pragma unroll
  for (int j = 32; j > 0; j >>= 1) {
    v0 = cswap(v0, j, true, lane);
    v1 = cswap(v1, j, true, lane);
  }
}

// ---------------- Kernel A: fp32 -> bf16 copy + row sq-norms ----------------
__global__ void knn_prep(const float* __restrict__ x, uint32* __restrict__ xbu,
                         float* __restrict__ sq) {
  const int row = blockIdx.x * 4 + (threadIdx.x >> 6);
  const int l = threadIdx.x & 63;
  const float2* xr = (const float2*)(x + (size_t)row * Dd);
  float s = 0.f;
#pragma unroll
  for (int q = 0; q < 4; ++q) {
    float2 v = xr[q * 64 + l];
    s = fmaf(v.x, v.x, s);
    s = fmaf(v.y, v.y, s);
    uint32 ux = __builtin_bit_cast(uint32, v.x);
    uint32 uy = __builtin_bit_cast(uint32, v.y);
    uint32 bx = (ux + 0x7FFFu + ((ux >> 16) & 1u)) >> 16;  // RNE to bf16
    uint32 by = (uy + 0x7FFFu + ((uy >> 16) & 1u)) >> 16;
    xbu[(size_t)row * (Dd / 2) + q * 64 + l] = bx | (by << 16);
  }
#pragma unroll
  for (int off = 32; off > 0; off >>= 1) s += __shfl_down(s, off);
  if (l == 0) sq[row] = s;
}

// ------- Kernel B: pipelined bf16-MFMA Gram tile + per-substream top-8 -------
// 2-D XCD partition: xcd=bid&7 owns a 1MB J-slice (4 sub-chunks of 256 rows);
// ib=bid>>5 keeps any 512-resident window to 16 A-tiles (2MB). A+B fit L2.
__global__ __launch_bounds__(256, 2) void knn_cand(
    const unsigned short* __restrict__ xb, const float* __restrict__ sq,
    uint32* __restrict__ partials) {
  __shared__ __align__(16) unsigned short stageS[2][TI * BKc * 2];  // 64 KB
  __shared__ float sqj[TJ];

  const int bid = blockIdx.x;
  const int xcd = bid & 7;
  const int jc = xcd * 4 + ((bid >> 3) & 3);  // [0,32)
  const int ib = bid >> 5;                    // [0,64)
  const int t = threadIdx.x;
  const int w = t >> 6;
  const int l = t & 63;
  const int wrow = w >> 1, wcol = w & 1;
  const int l16 = l & 15, lq = l >> 4;

  const int row_s = t >> 1;
  const int hv = t & 1;
  const int irow_g = ib * TI + row_s;
  const int arow0 = ib * TI;

  float (*d2s)[32] = (float(*)[32])(void*)stageS[1];

#define STAGE(buf, brow0, kkk)                                              \
  do {                                                                      \
    _Pragma("unroll") for (int u = 0; u < 4; ++u) {                         \
      const int ch = w * 4 + u;                                             \
      const int r = ch * 8 + (l >> 3);                                      \
      const int cs = ((l & 7) ^ (r & 7)) * 8;                               \
      gload_lds16(xb + (size_t)(arow0 + r) * Dd + (kkk)*BKc + cs,           \
                  (void*)(stageS[buf] + ch * 512));                         \
      gload_lds16(xb + (size_t)(brow0 + r) * Dd + (kkk)*BKc + cs,           \
                  (void*)(stageS[buf] + TI * BKc + ch * 512));              \
    }                                                                       \
  } while (0)

  uint32 heap[CSUB];
#pragma unroll
  for (int s = 0; s < CSUB; ++s) heap[s] = 0xFFFFFFFFu;

  const int jbase0 = jc * (Nn / JSPLIT);
  STAGE(0, jbase0, 0);  // prologue: jt=0, kk=0 into buf0

  for (int jt = 0; jt < JTILES; ++jt) {
    const int jbase = jbase0 + jt * TJ;
    __syncthreads();  // [A] drains prologue / cross-jt prefetch; protects d2s

    f32x4 acc[4][4];
#pragma unroll
    for (int a = 0; a < 4; ++a)
#pragma unroll
      for (int b = 0; b < 4; ++b) acc[a][b] = (f32x4){0.f, 0.f, 0.f, 0.f};

#pragma unroll
    for (int kk = 0; kk < Dd / BKc; ++kk) {
      const int cb = kk & 1;
      if (kk < Dd / BKc - 1) {
        STAGE(cb ^ 1, jbase, kk + 1);
      } else if (jt < JTILES - 1) {
        STAGE(cb ^ 1, jbase + TJ, 0);  // cross-jt prefetch (lands during scan)
      }
      const unsigned short* AL = stageS[cb];
      const unsigned short* BLp = stageS[cb] + TI * BKc;
#pragma unroll
      for (int ks = 0; ks < 2; ++ks) {
        bf16x8 af[4], bfr[4];
#pragma unroll
        for (int fi = 0; fi < 4; ++fi) {
          const int R = wrow * 64 + fi * 16 + l16;
          af[fi] = *(const bf16x8*)&AL[R * BKc +
                                       ((ks * 32 + lq * 8) ^ ((R & 7) * 8))];
        }
#pragma unroll
        for (int fj = 0; fj < 4; ++fj) {
          const int R = wcol * 64 + fj * 16 + l16;
          bfr[fj] = *(const bf16x8*)&BLp[R * BKc +
                                         ((ks * 32 + lq * 8) ^ ((R & 7) * 8))];
        }
#pragma unroll
        for (int fi = 0; fi < 4; ++fi)
#pragma unroll
          for (int fj = 0; fj < 4; ++fj)
            acc[fi][fj] = __builtin_amdgcn_mfma_f32_16x16x32_bf16(
                af[fi], bfr[fj], acc[fi][fj], 0, 0, 0);
      }
      __syncthreads();  // [C] drains this kk's prefetch; orders buffer reuse
    }

    if (t < TJ) sqj[t] = sq[jbase + t];

    // Four 32-col phases: stage dots to d2s (aliases buf1, free now), scan.
#pragma unroll
    for (int p = 0; p < 4; ++p) {
      __syncthreads();  // [D] previous phase's scan reads done (+sqj visible)
      if (wcol == (p >> 1)) {
        const int fjp = p & 1;
#pragma unroll
        for (int fi = 0; fi < 4; ++fi)
#pragma unroll
          for (int fjh = 0; fjh < 2; ++fjh) {
            const int fj = fjp * 2 + fjh;
#pragma unroll
            for (int r = 0; r < 4; ++r) {
              const int row = wrow * 64 + fi * 16 + lq * 4 + r;
              const int c = fjh * 16 + l16;
              const int cs2 = (((c >> 2) ^ (row & 7)) << 2) | (c & 3);
              d2s[row][cs2] = acc[fi][fj][r];
            }
          }
      }
      __syncthreads();  // [E] d2s writes visible
      const uint32 jg0 = (uint32)(jbase + p * 32 + hv * 16);
#pragma unroll
      for (int u2 = 0; u2 < 4; ++u2) {
        const int chunk = (hv * 4 + u2) ^ (row_s & 7);
        float4 v = *(const float4*)&d2s[row_s][chunk * 4];
        float vv[4] = {v.x, v.y, v.z, v.w};
#pragma unroll
        for (int e = 0; e < 4; ++e) {
          float key =
              fmaxf(fmaf(-2.f, vv[e], sqj[p * 32 + hv * 16 + u2 * 4 + e]), 0.f);
          uint32 packed = (__builtin_bit_cast(uint32, key) & 0xFFFFE000u) |
                          (jg0 + (uint32)(u2 * 4 + e));
          topk_insert<CSUB>(heap, packed);  // self removed later in rescore
        }
      }
    }
  }

  const int sub = jc * 2 + hv;  // [0,64)
#pragma unroll
  for (int s = 0; s < CSUB; ++s)
    partials[(size_t)irow_g * PENT + sub * CSUB + s] = heap[s];
#undef STAGE
}

// ---- Kernel C: shfl-bitonic merge -> fp64 rescore -> average (re-gather) ----
__global__ __launch_bounds__(256) void knn_rescore(
    const float* __restrict__ x, const uint32* __restrict__ partials,
    float* __restrict__ out) {
  __shared__ uint32 topS[128];  // per-wave top-32 survivors
  __shared__ int candS[CC];
  __shared__ double d2S[CC];
  __shared__ int selS[KK];
  const int row = blockIdx.x;
  const int t = threadIdx.x, w = t >> 6, l = t & 63;

  // Phase 1: each wave sorts its 128 partial entries fully in registers.
  {
    const uint32* prow = partials + (size_t)row * PENT + w * 128;
    uint32 v0 = prow[l];
    uint32 v1 = prow[64 + l];
    if ((v0 & 0x1FFFu) == (uint32)row) v0 = 0xFFFFFFFFu;  // drop self
    if ((v1 & 0x1FFFu) == (uint32)row) v1 = 0xFFFFFFFFu;
    sort128(v0, v1, l);
    if (l < 32) topS[w * 32 + l] = v0;  // wave's 32 smallest
  }
  __syncthreads();
  // Phase 2: wave 0 sorts the 4x32 survivors; first 32 = exact global top-32.
  if (w == 0) {
    uint32 u0 = topS[l], u1 = topS[64 + l];
    sort128(u0, u1, l);
    if (l < 32) candS[l] = (int)(u0 & 0x1FFFu);
  }
  __syncthreads();

  // Phase 3: exact fp64 rescore of the 32 candidates (8 per wave).
  const float4* x4 = (const float4*)x;
  float4 xi0 = x4[(size_t)row * 128 + l];
  float4 xi1 = x4[(size_t)row * 128 + 64 + l];
#pragma unroll
  for (int u = 0; u < 8; ++u) {
    const int c = w * 8 + u;
    const int j = candS[c];
    float4 b0 = x4[(size_t)j * 128 + l];
    float4 b1 = x4[(size_t)j * 128 + 64 + l];
    double s = 0.0;
    double d0 = (double)xi0.x - (double)b0.x;
    double d1 = (double)xi0.y - (double)b0.y;
    double d2 = (double)xi0.z - (double)b0.z;
    double d3 = (double)xi0.w - (double)b0.w;
    s = fma(d0, d0, s); s = fma(d1, d1, s); s = fma(d2, d2, s); s = fma(d3, d3, s);
    d0 = (double)xi1.x - (double)b1.x;
    d1 = (double)xi1.y - (double)b1.y;
    d2 = (double)xi1.z - (double)b1.z;
    d3 = (double)xi1.w - (double)b1.w;
    s = fma(d0, d0, s); s = fma(d1, d1, s); s = fma(d2, d2, s); s = fma(d3, d3, s);
#pragma unroll
    for (int off = 32; off > 0; off >>= 1) s += __shfl_down(s, off);
    if (l == 0) d2S[c] = s;
  }
  __syncthreads();
  // Phase 4: rank among 32 (ties broken by index, matching stable argsort).
  if (t < CC) {
    const double mine = d2S[t];
    const int mi = candS[t];
    int rank = 0;
#pragma unroll
    for (int o = 0; o < CC; ++o) {
      double vo = d2S[o];
      int io = candS[o];
      if (vo < mine || (vo == mine && io < mi)) rank++;
    }
    if (rank < KK) selS[rank] = mi;
  }
  __syncthreads();
  // Phase 5: average the 16 selected rows (coalesced re-gather, L2/L3-hot).
  const float2* x2 = (const float2*)x;
  float ax = 0.f, ay = 0.f;
#pragma unroll
  for (int n = 0; n < KK; ++n) {
    float2 vb = x2[(size_t)selS[n] * 256 + t];
    ax += vb.x;
    ay += vb.y;
  }
  ((float2*)out)[(size_t)row * 256 + t] = make_float2(ax * 0.0625f, ay * 0.0625f);
}

extern "C" void kernel_launch(void* const* d_in, const int* in_sizes, int n_in,
                              void* d_out, int out_size, void* d_ws,
                              size_t ws_size, hipStream_t stream) {
  const float* x = (const float*)d_in[0];
  float* out = (float*)d_out;
  char* ws = (char*)d_ws;
  // ws layout: xb (8MB) | sq (32KB) | partials (16MB)  => 24.2 MB
  unsigned short* xb = (unsigned short*)ws;
  float* sq = (float*)(ws + (size_t)Nn * Dd * 2);
  uint32* partials = (uint32*)(ws + (size_t)Nn * Dd * 2 + (size_t)Nn * 4);

  knn_prep<<<Nn / 4, 256, 0, stream>>>(x, (uint32*)xb, sq);
  knn_cand<<<64 * JSPLIT, 256, 0, stream>>>(xb, sq, partials);
  knn_rescore<<<Nn, 256, 0, stream>>>(x, partials, out);
}